// Round 18
// baseline (130.587 us; speedup 1.0000x reference)
//
#include <hip/hip_runtime.h>
#include <hip/hip_fp16.h>

#define HC 16
#define CIN 16
#define BD 31
#define HH 128
#define WW 128
#define PLANE (HH*WW)           // 16384
#define CH_STRIDE (BD*PLANE)    // 507904

typedef __attribute__((ext_vector_type(8))) short bf16x8;   // 8 bf16 = 4 VGPR
typedef __attribute__((ext_vector_type(16))) float f32x16;  // MFMA 32x32 acc

#define LOG2E 1.442695041f

__device__ __forceinline__ ushort f2bf(float f) {   // RNE float->bf16 (prep paths)
    unsigned u = __float_as_uint(f);
    u = (u + 0x7fffu + ((u >> 16) & 1u)) >> 16;
    return (ushort)u;
}
// packed f32x2 -> bf16x2 via HW cvt_pk (no builtin on gfx950 — inline asm, T12)
__device__ __forceinline__ unsigned pack_bf2(float lo, float hi) {
    unsigned r;
    asm("v_cvt_pk_bf16_f32 %0, %1, %2" : "=v"(r) : "v"(lo), "v"(hi));
    return r;
}
// paired sigmoids from log2-domain negated args (exp2 direct, shared rcp)
__device__ __forceinline__ float2 sigmoid2l(float na, float nb) {
    float ea = __builtin_amdgcn_exp2f(na);
    float eb = __builtin_amdgcn_exp2f(nb);
    float pa = 1.0f + ea, pb = 1.0f + eb;
    float r  = __builtin_amdgcn_rcpf(pa * pb);
    return make_float2(pb * r, pa * r);      // 1/pa, 1/pb
}
// paired tanh-form gelus (|err vs exact-erf gelu| <~5e-4), shared rcp:
// gelu(x) = x * sigma(1.5957691*(x + 0.044715*x^3)); 1.5957691*log2e = 2.3021841
__device__ __forceinline__ float2 gelu2(float x, float y) {
    float ux = fmaf(0.044715f * x, x * x, x);
    float uy = fmaf(0.044715f * y, y * y, y);
    float ex = __builtin_amdgcn_exp2f(-2.3021841f * ux);
    float ey = __builtin_amdgcn_exp2f(-2.3021841f * uy);
    float px = 1.0f + ex, py = 1.0f + ey;
    float r  = __builtin_amdgcn_rcpf(px * py);
    return make_float2(x * py * r, y * px * r);
}

// ---------------------------------------------------------------------------
// xprep + weight prep in ONE launch (unchanged from r17).
// ---------------------------------------------------------------------------
__global__ __launch_bounds__(256)
void xprep_kernel(const float* __restrict__ inp, char* __restrict__ xT,
                  const float* __restrict__ cw,
                  const float* __restrict__ w1,
                  const float* __restrict__ w2,
                  const float* __restrict__ w3,
                  ushort* __restrict__ wtab, ushort* __restrict__ wtab2)
{
    if (blockIdx.x >= 7936) {                 // weight-prep blocks
        int idx = (blockIdx.x - 7936) * 256 + threadIdx.x;
        if (idx < 13824) {
            int j    = idx & 7;
            int lane = (idx >> 3) & 63;
            int t    = (idx >> 9) % 9;
            int kd   = (idx >> 9) / 9;
            int co = lane & 31;
            int ci = 8 * (lane >> 5) + j;
            int kh = t / 3, kw = t % 3;
            wtab[idx] = f2bf(cw[(co * CIN + ci) * 27 + kd * 9 + kh * 3 + kw]);
            return;
        }
        idx -= 13824;
        if (idx >= 2048) return;
        int e    = idx & 7;
        int lane = (idx >> 3) & 63;
        int tbl  = idx >> 9;
        int m  = lane & 31;
        int hi = lane >> 5;
        int k  = (e & 3) + 8 * (e >> 2) + 4 * hi;   // shared k-permutation
        float v = 0.f;
        if (tbl == 0)      v = w1[k * 32 + m];
        else if (tbl == 3) v = w3[k * 32 + m];
        else {
            int mf = tbl - 1;
            if (m < 16) v = w2[(k + 16 * mf) * 16 + m];
        }
        wtab2[idx] = f2bf(v);
        return;
    }

    __shared__ float tile[16][256];
    int t  = threadIdx.x;
    int hp = blockIdx.x & 63;
    int g  = blockIdx.x >> 6;
    int d  = g % BD;
    int b  = g / BD;

    size_t src = (size_t)b * CIN * CH_STRIDE + (size_t)d * PLANE + hp * 256;
    #pragma unroll
    for (int c = 0; c < 16; ++c)
        tile[c][t] = inp[src + (size_t)c * CH_STRIDE + t];
    __syncthreads();

    int w  = t & 127;
    int rr = t >> 7;
    char* rowp = xT + (((size_t)(b * BD + d) * 128) + hp * 2 + rr) * 4096;
    #pragma unroll
    for (int q = 0; q < 2; ++q) {
        uint4 pk;
        pk.x = (unsigned)f2bf(tile[q*8+0][t]) | ((unsigned)f2bf(tile[q*8+1][t]) << 16);
        pk.y = (unsigned)f2bf(tile[q*8+2][t]) | ((unsigned)f2bf(tile[q*8+3][t]) << 16);
        pk.z = (unsigned)f2bf(tile[q*8+4][t]) | ((unsigned)f2bf(tile[q*8+5][t]) << 16);
        pk.w = (unsigned)f2bf(tile[q*8+6][t]) | ((unsigned)f2bf(tile[q*8+7][t]) << 16);
        unsigned off = ((unsigned)((w + 1) * 32 + q * 16) ^ (((unsigned)(w + 1) & 0xE) << 3)) - 32;
        *(uint4*)(rowp + off) = pk;
    }
}

// ---------------------------------------------------------------------------
// FUSED conv+scan+MLP — r17 numerics, 6-SLOT RING / 2 OUTPUTS PER BARRIER.
// Super-step (i,i+1): stage planes j=i+3,i+4 -> conv(i) ∥ tail(i-1) ∥
// conv(i+1) ∥ tail(i) -> ONE barrier. Slot residues: reads {i-1..i+2},
// writes {i+3,i+4} mod 6 — six consecutive residues, all distinct (no race);
// staged slots first read one barrier later (vmcnt drained by s_barrier).
// Halves barrier count (31->17) and doubles the scheduling region.
// Slots indexed by SCAN position j (plane = d0+sgn*j); A-frags loaded in
// scan-role order: af[m*9+t] with kd = rev ? 2-m : m.
// ---------------------------------------------------------------------------
#define SLOT_B (3 * 4224)       // 12672 B per plane slot; 6 slots = 76032 B

__device__ __forceinline__ void gload_lds16(const void* g, void* l) {
    __builtin_amdgcn_global_load_lds(
        (const __attribute__((address_space(1))) unsigned int*)g,
        (__attribute__((address_space(3))) unsigned int*)l, 16, 0, 0);
}

__global__ __launch_bounds__(256, 2)
void qrnn_fused(const char* __restrict__ xT,
                const ushort* __restrict__ wtab,
                const ushort* __restrict__ wtab2,
                float* __restrict__ out,
                const int* __restrict__ rev_p)
{
    __shared__ __align__(16) char slab[6][SLOT_B];

    // grid 512 = 8 XCD x 64
    int p = blockIdx.x;
    int logical = (p & 7) * 64 + (p >> 3);
    int b  = logical >> 7;
    int ht = logical & 127;
    int rev = rev_p[0];
    int sgn = rev ? -1 : 1;
    int d0  = rev ? (BD - 1) : 0;

    int lane = threadIdx.x & 63;
    int wid  = threadIdx.x >> 6;
    int wl   = lane & 31;
    int hi   = lane >> 5;
    int cio  = hi * 16;

    // A-frags in scan-role order: slot position m (j-1+m) has d-offset
    // sgn*(m-1), i.e. kd = rev ? 2-m : m.
    const bf16x8* wt = (const bf16x8*)wtab;
    bf16x8 af[27];
    #pragma unroll
    for (int m = 0; m < 3; ++m) {
        int kd = rev ? (2 - m) : m;
        #pragma unroll
        for (int t = 0; t < 9; ++t)
            af[m * 9 + t] = wt[(kd * 9 + t) * 64 + lane];
    }

    const bf16x8* W2 = (const bf16x8*)wtab2;
    bf16x8 af1  = W2[lane];
    bf16x8 af2a = W2[64 + lane];
    bf16x8 af2b = W2[128 + lane];
    bf16x8 af3  = W2[192 + lane];

    unsigned bpo[3];
    #pragma unroll
    for (int dwn = 0; dwn < 3; ++dwn) {
        unsigned wc = (unsigned)(wl + dwn);
        bpo[dwn] = (unsigned)(wid * 1024) + ((wc * 32 + cio) ^ ((wc & 0xE) << 3));
    }

    // zero w-edge columns of all 6 slots: per row, [0,32) and [4128,4224)
    for (int i = threadIdx.x; i < 6 * 3 * 32; i += 256) {
        int s = i / 96;
        int r = (i / 32) % 3;
        int k = i & 31;
        int off = (k < 8) ? (k * 4) : (4128 + (k - 8) * 4);
        *(int*)(slab[s] + r * 4224 + off) = 0;
    }

    auto zero_slot = [&](int s) {    // interior only (edges already zero)
        for (int i = threadIdx.x; i < 768; i += 256) {
            int r = i >> 8;
            int k = i & 255;
            *(uint4*)(slab[s] + r * 4224 + 32 + k * 16) = uint4{0, 0, 0, 0};
        }
    };

    // stage plane at scan index j (0..30) into slot j%6
    auto stage = [&](int j) {
        int plane = d0 + sgn * j;
        const char* pl = xT + ((size_t)(b * BD + plane) * 128) * 4096;
        char* sb = slab[j % 6];
        for (int c = wid; c < 12; c += 4) {
            int rr = c >> 2, ch = c & 3;
            int h = ht - 1 + rr;
            char* dst = sb + rr * 4224 + 32 + ch * 1024;
            if ((unsigned)h < (unsigned)HH)
                gload_lds16(pl + (size_t)h * 4096 + ch * 1024 + lane * 16, dst);
            else
                *(uint4*)(dst + lane * 16) = uint4{0, 0, 0, 0};
        }
    };

    f32x16 zacc;
    #pragma unroll
    for (int r = 0; r < 16; ++r) zacc[r] = 0.f;

    // conv for output at scan index j: reads slots j-1, j, j+1
    auto convd = [&](int j) -> f32x16 {
        f32x16 A = zacc;
        #pragma unroll
        for (int m = 0; m < 3; ++m) {
            const char* sb = slab[(j - 1 + m + 6) % 6];
            #pragma unroll
            for (int t = 0; t < 9; ++t) {
                bf16x8 bfr = *(const bf16x8*)(sb + (t / 3) * 4224 + bpo[t % 3]);
                A = __builtin_amdgcn_mfma_f32_32x32x16_bf16(af[m * 9 + t], bfr, A, 0, 0, 0);
            }
        }
        return A;
    };

    float h[8];
    #pragma unroll
    for (int j = 0; j < 8; ++j) h[j] = 0.f;

    float* obase = out + (size_t)b * HC * CH_STRIDE + ht * WW + wid * 32 + wl;

    // tail: gates -> scan -> MLP -> store for output plane d, given conv acc A.
    auto tail = [&](const f32x16& A, int d) {
        union { bf16x8 v; unsigned u[4]; } bx;
        #pragma unroll
        for (int r = 0; r < 8; ++r) {
            float2 s = sigmoid2l(-2.0f * LOG2E * A[r], -LOG2E * A[r + 8]);
            float z = fmaf(2.0f, s.x, -1.0f);    // tanh via sigmoid
            float f = s.y;
            h[r] = z + f * (h[r] - z);           // f*h + (1-f)*z
        }
        #pragma unroll
        for (int q = 0; q < 4; ++q)
            bx.u[q] = pack_bf2(h[2 * q], h[2 * q + 1]);

        f32x16 a1 = __builtin_amdgcn_mfma_f32_32x32x16_bf16(af1, bx.v, zacc, 0, 0, 0);
        f32x16 a3 = __builtin_amdgcn_mfma_f32_32x32x16_bf16(af3, bx.v, zacc, 0, 0, 0);

        union { bf16x8 v; unsigned u[4]; } b2a, b2b;
        #pragma unroll
        for (int q = 0; q < 4; ++q) {
            float2 ga = gelu2(a1[2 * q],     a1[2 * q + 1]);
            float2 gb = gelu2(a1[8 + 2 * q], a1[8 + 2 * q + 1]);
            b2a.u[q] = pack_bf2(ga.x, ga.y);
            b2b.u[q] = pack_bf2(gb.x, gb.y);
        }
        f32x16 a2 = __builtin_amdgcn_mfma_f32_32x32x16_bf16(af2a, b2a.v, zacc, 0, 0, 0);
        a2 = __builtin_amdgcn_mfma_f32_32x32x16_bf16(af2b, b2b.v, a2, 0, 0, 0);

        float* ob = obase + (size_t)d * PLANE;
        #pragma unroll
        for (int q = 0; q < 4; ++q) {
            float2 s = sigmoid2l(-LOG2E * a3[8 + 2 * q], -LOG2E * a3[9 + 2 * q]);
            int c0 = (2 * q     & 3) + 8 * (2 * q     >> 2) + 4 * hi;
            int c1 = (2 * q + 1 & 3) + 8 * (2 * q + 1 >> 2) + 4 * hi;
            ob[(size_t)c0 * CH_STRIDE] = fmaf(a3[2 * q],     s.x, a2[2 * q]);
            ob[(size_t)c1 * CH_STRIDE] = fmaf(a3[2 * q + 1], s.y, a2[2 * q + 1]);
        }
    };

    // prologue: j=-1 zeros in slot 5; planes j=0..3 staged (slots 0..3)
    zero_slot(5);
    stage(0); stage(1); stage(2); stage(3);
    __syncthreads();

    // peeled output 0 (reads slots 5,0,1); barrier before loop overwrites slot 5
    f32x16 accP = convd(0);
    __syncthreads();

    #pragma unroll 1
    for (int i = 1; i < BD; i += 2) {            // i = 1,3,...,29
        int js0 = i + 3, js1 = i + 4;
        if (js0 <= BD - 1) stage(js0);
        else if (js0 == BD) zero_slot(js0 % 6);  // j=31 OOB -> zeros
        if (js1 <= BD - 1) stage(js1);
        else if (js1 == BD) zero_slot(js1 % 6);

        f32x16 a0 = convd(i);                    // 27 MFMAs
        tail(accP, d0 + sgn * (i - 1));          // output i-1
        f32x16 a1 = convd(i + 1);                // 27 MFMAs
        tail(a0, d0 + sgn * i);                  // output i
        accP = a1;

        __syncthreads();                         // staged planes landed
    }
    tail(accP, d0 + sgn * (BD - 1));             // output 30
}

extern "C" void kernel_launch(void* const* d_in, const int* in_sizes, int n_in,
                              void* d_out, int out_size, void* d_ws, size_t ws_size,
                              hipStream_t stream)
{
    const float* inp = (const float*)d_in[0];
    const float* cw  = (const float*)d_in[1];
    const float* w1  = (const float*)d_in[2];
    const float* w2  = (const float*)d_in[3];
    const float* w3  = (const float*)d_in[4];
    const int*   rev = (const int*)d_in[5];

    ushort* wtab  = (ushort*)d_ws;                    // [0, 27648)
    ushort* wtab2 = (ushort*)((char*)d_ws + 27648);   // [27648, 31744)
    char*   xT    = (char*)d_ws + 32768;              // 65,011,712 B

    // 7936 xprep blocks + 62 weight-prep blocks, one launch
    xprep_kernel<<<dim3(7998), dim3(256), 0, stream>>>(
        inp, xT, cw, w1, w2, w3, wtab, wtab2);

    // 4b x 128ht = 512 blocks (2 per CU), persistent over all 31 d
    qrnn_fused<<<dim3(512), dim3(256), 0, stream>>>(
        xT, wtab, wtab2, (float*)d_out, rev);
}

// Round 19
// 127.627 us; speedup vs baseline: 1.0232x; 1.0232x over previous
//
#include <hip/hip_runtime.h>
#include <hip/hip_fp16.h>

#define HC 16
#define CIN 16
#define BD 31
#define HH 128
#define WW 128
#define PLANE (HH*WW)           // 16384
#define CH_STRIDE (BD*PLANE)    // 507904

typedef __attribute__((ext_vector_type(8))) short bf16x8;   // 8 bf16 = 4 VGPR
typedef __attribute__((ext_vector_type(16))) float f32x16;  // MFMA 32x32 acc

#define LOG2E 1.442695041f

__device__ __forceinline__ ushort f2bf(float f) {   // RNE float->bf16 (prep paths)
    unsigned u = __float_as_uint(f);
    u = (u + 0x7fffu + ((u >> 16) & 1u)) >> 16;
    return (ushort)u;
}
// packed f32x2 -> bf16x2 via HW cvt_pk (no builtin on gfx950 — inline asm, T12)
__device__ __forceinline__ unsigned pack_bf2(float lo, float hi) {
    unsigned r;
    asm("v_cvt_pk_bf16_f32 %0, %1, %2" : "=v"(r) : "v"(lo), "v"(hi));
    return r;
}
// paired sigmoids from log2-domain negated args: returns (sig(a), sig(b))
// where na = -a*log2e, nb = -b*log2e. One shared rcp; exp via v_exp_f32
// directly (ln2 folded into the callers' pre-scale constants).
__device__ __forceinline__ float2 sigmoid2l(float na, float nb) {
    float ea = __builtin_amdgcn_exp2f(na);
    float eb = __builtin_amdgcn_exp2f(nb);
    float pa = 1.0f + ea, pb = 1.0f + eb;
    float r  = __builtin_amdgcn_rcpf(pa * pb);
    return make_float2(pb * r, pa * r);      // 1/pa, 1/pb
}
// paired tanh-form gelus (|err vs exact-erf gelu| <~5e-4), shared rcp:
// gelu(x) = x * sigma(1.5957691*(x + 0.044715*x^3)); 1.5957691*log2e = 2.3021841
__device__ __forceinline__ float2 gelu2(float x, float y) {
    float ux = fmaf(0.044715f * x, x * x, x);
    float uy = fmaf(0.044715f * y, y * y, y);
    float ex = __builtin_amdgcn_exp2f(-2.3021841f * ux);
    float ey = __builtin_amdgcn_exp2f(-2.3021841f * uy);
    float px = 1.0f + ex, py = 1.0f + ey;
    float r  = __builtin_amdgcn_rcpf(px * py);
    return make_float2(x * py * r, y * px * r);
}

// ---------------------------------------------------------------------------
// xprep + weight prep in ONE launch. Blocks < 7936: fp32 -> bf16 rows
// xT[b][d][h][4096B], slab swizzle pre-baked (swizzle-source + linear
// gload_lds dest, rule #21). Blocks >= 7936 (62): conv wtab (co=lane&31,
// ci=8*(lane>>5)+j) and MLP wtab2 (shared k-map k(e,hi)=(e&3)+8*(e>>2)+4*hi).
// ---------------------------------------------------------------------------
__global__ __launch_bounds__(256)
void xprep_kernel(const float* __restrict__ inp, char* __restrict__ xT,
                  const float* __restrict__ cw,
                  const float* __restrict__ w1,
                  const float* __restrict__ w2,
                  const float* __restrict__ w3,
                  ushort* __restrict__ wtab, ushort* __restrict__ wtab2)
{
    if (blockIdx.x >= 7936) {                 // weight-prep blocks
        int idx = (blockIdx.x - 7936) * 256 + threadIdx.x;
        if (idx < 13824) {
            int j    = idx & 7;
            int lane = (idx >> 3) & 63;
            int t    = (idx >> 9) % 9;
            int kd   = (idx >> 9) / 9;
            int co = lane & 31;
            int ci = 8 * (lane >> 5) + j;
            int kh = t / 3, kw = t % 3;
            wtab[idx] = f2bf(cw[(co * CIN + ci) * 27 + kd * 9 + kh * 3 + kw]);
            return;
        }
        idx -= 13824;
        if (idx >= 2048) return;
        int e    = idx & 7;
        int lane = (idx >> 3) & 63;
        int tbl  = idx >> 9;
        int m  = lane & 31;
        int hi = lane >> 5;
        int k  = (e & 3) + 8 * (e >> 2) + 4 * hi;   // shared k-permutation
        float v = 0.f;
        if (tbl == 0)      v = w1[k * 32 + m];
        else if (tbl == 3) v = w3[k * 32 + m];
        else {
            int mf = tbl - 1;
            if (m < 16) v = w2[(k + 16 * mf) * 16 + m];
        }
        wtab2[idx] = f2bf(v);
        return;
    }

    __shared__ float tile[16][256];
    int t  = threadIdx.x;
    int hp = blockIdx.x & 63;
    int g  = blockIdx.x >> 6;
    int d  = g % BD;
    int b  = g / BD;

    size_t src = (size_t)b * CIN * CH_STRIDE + (size_t)d * PLANE + hp * 256;
    #pragma unroll
    for (int c = 0; c < 16; ++c)
        tile[c][t] = inp[src + (size_t)c * CH_STRIDE + t];
    __syncthreads();

    int w  = t & 127;
    int rr = t >> 7;
    char* rowp = xT + (((size_t)(b * BD + d) * 128) + hp * 2 + rr) * 4096;
    #pragma unroll
    for (int q = 0; q < 2; ++q) {
        uint4 pk;
        pk.x = (unsigned)f2bf(tile[q*8+0][t]) | ((unsigned)f2bf(tile[q*8+1][t]) << 16);
        pk.y = (unsigned)f2bf(tile[q*8+2][t]) | ((unsigned)f2bf(tile[q*8+3][t]) << 16);
        pk.z = (unsigned)f2bf(tile[q*8+4][t]) | ((unsigned)f2bf(tile[q*8+5][t]) << 16);
        pk.w = (unsigned)f2bf(tile[q*8+6][t]) | ((unsigned)f2bf(tile[q*8+7][t]) << 16);
        unsigned off = ((unsigned)((w + 1) * 32 + q * 16) ^ (((unsigned)(w + 1) & 0xE) << 3)) - 32;
        *(uint4*)(rowp + off) = pk;
    }
}

// ---------------------------------------------------------------------------
// FUSED conv+scan+MLP — r17 structure (measured best: 128.8 µs total):
// single-chain convd, software-pipelined conv(d) ∥ tail(d-1), TRANS-reduced
// tail with exp2-folded activations. One barrier per d; 4 rolling plane slots.
// ---------------------------------------------------------------------------
#define SLOT_B (3 * 4224)       // 12672 B per plane slot

__device__ __forceinline__ void gload_lds16(const void* g, void* l) {
    __builtin_amdgcn_global_load_lds(
        (const __attribute__((address_space(1))) unsigned int*)g,
        (__attribute__((address_space(3))) unsigned int*)l, 16, 0, 0);
}

__global__ __launch_bounds__(256, 2)
void qrnn_fused(const char* __restrict__ xT,
                const ushort* __restrict__ wtab,
                const ushort* __restrict__ wtab2,
                float* __restrict__ out,
                const int* __restrict__ rev_p)
{
    __shared__ __align__(16) char slab[4][SLOT_B];

    // grid 512 = 8 XCD x 64
    int p = blockIdx.x;
    int logical = (p & 7) * 64 + (p >> 3);
    int b  = logical >> 7;
    int ht = logical & 127;
    int rev = rev_p[0];

    int lane = threadIdx.x & 63;
    int wid  = threadIdx.x >> 6;
    int wl   = lane & 31;
    int hi   = lane >> 5;
    int cio  = hi * 16;

    const bf16x8* wt = (const bf16x8*)wtab;
    bf16x8 af[27];
    #pragma unroll
    for (int t = 0; t < 27; ++t) af[t] = wt[t * 64 + lane];

    const bf16x8* W2 = (const bf16x8*)wtab2;
    bf16x8 af1  = W2[lane];
    bf16x8 af2a = W2[64 + lane];
    bf16x8 af2b = W2[128 + lane];
    bf16x8 af3  = W2[192 + lane];

    unsigned bpo[3];
    #pragma unroll
    for (int dwn = 0; dwn < 3; ++dwn) {
        unsigned wc = (unsigned)(wl + dwn);
        bpo[dwn] = (unsigned)(wid * 1024) + ((wc * 32 + cio) ^ ((wc & 0xE) << 3));
    }

    for (int i = threadIdx.x; i < 4 * 3 * 32; i += 256) {
        int s = i / 96;
        int r = (i / 32) % 3;
        int k = i & 31;
        int off = (k < 8) ? (k * 4) : (4128 + (k - 8) * 4);
        *(int*)(slab[s] + r * 4224 + off) = 0;
    }

    auto zero_slot = [&](int s) {
        for (int i = threadIdx.x; i < 768; i += 256) {
            int r = i >> 8;
            int k = i & 255;
            *(uint4*)(slab[s] + r * 4224 + 32 + k * 16) = uint4{0, 0, 0, 0};
        }
    };

    auto stage = [&](int s, int plane) {
        const char* pl = xT + ((size_t)(b * BD + plane) * 128) * 4096;
        for (int c = wid; c < 12; c += 4) {
            int rr = c >> 2, ch = c & 3;
            int h = ht - 1 + rr;
            char* dst = slab[s] + rr * 4224 + 32 + ch * 1024;
            if ((unsigned)h < (unsigned)HH)
                gload_lds16(pl + (size_t)h * 4096 + ch * 1024 + lane * 16, dst);
            else
                *(uint4*)(dst + lane * 16) = uint4{0, 0, 0, 0};
        }
    };

    f32x16 zacc;
    #pragma unroll
    for (int r = 0; r < 16; ++r) zacc[r] = 0.f;

    // conv for output d: single 27-MFMA chain (measured best vs split forms)
    auto convd = [&](int d) -> f32x16 {
        f32x16 A = zacc;
        #pragma unroll
        for (int kd = 0; kd < 3; ++kd) {
            const char* sb = slab[(d - 1 + kd) & 3];   // OOB slots hold zeros
            #pragma unroll
            for (int t = 0; t < 9; ++t) {
                bf16x8 bfr = *(const bf16x8*)(sb + (t / 3) * 4224 + bpo[t % 3]);
                A = __builtin_amdgcn_mfma_f32_32x32x16_bf16(af[kd * 9 + t], bfr, A, 0, 0, 0);
            }
        }
        return A;
    };

    float h[8];
    #pragma unroll
    for (int j = 0; j < 8; ++j) h[j] = 0.f;

    float* obase = out + (size_t)b * HC * CH_STRIDE + ht * WW + wid * 32 + wl;

    // tail: gates -> scan -> MLP -> store for plane d, given conv acc A.
    auto tail = [&](const f32x16& A, int d) {
        union { bf16x8 v; unsigned u[4]; } bx;
        #pragma unroll
        for (int r = 0; r < 8; ++r) {
            // z = tanh(a) = 2*sig(2a)-1 -> exp2 arg -2a*log2e; f = sig(b)
            float2 s = sigmoid2l(-2.0f * LOG2E * A[r], -LOG2E * A[r + 8]);
            float z = fmaf(2.0f, s.x, -1.0f);
            float f = s.y;
            h[r] = z + f * (h[r] - z);           // f*h + (1-f)*z
        }
        #pragma unroll
        for (int q = 0; q < 4; ++q)
            bx.u[q] = pack_bf2(h[2 * q], h[2 * q + 1]);

        f32x16 a1 = __builtin_amdgcn_mfma_f32_32x32x16_bf16(af1, bx.v, zacc, 0, 0, 0);
        f32x16 a3 = __builtin_amdgcn_mfma_f32_32x32x16_bf16(af3, bx.v, zacc, 0, 0, 0);

        union { bf16x8 v; unsigned u[4]; } b2a, b2b;
        #pragma unroll
        for (int q = 0; q < 4; ++q) {
            float2 ga = gelu2(a1[2 * q],     a1[2 * q + 1]);
            float2 gb = gelu2(a1[8 + 2 * q], a1[8 + 2 * q + 1]);
            b2a.u[q] = pack_bf2(ga.x, ga.y);
            b2b.u[q] = pack_bf2(gb.x, gb.y);
        }
        f32x16 a2 = __builtin_amdgcn_mfma_f32_32x32x16_bf16(af2a, b2a.v, zacc, 0, 0, 0);
        a2 = __builtin_amdgcn_mfma_f32_32x32x16_bf16(af2b, b2b.v, a2, 0, 0, 0);

        float* ob = obase + (size_t)d * PLANE;
        #pragma unroll
        for (int q = 0; q < 4; ++q) {
            float2 s = sigmoid2l(-LOG2E * a3[8 + 2 * q], -LOG2E * a3[9 + 2 * q]);
            int c0 = (2 * q     & 3) + 8 * (2 * q     >> 2) + 4 * hi;
            int c1 = (2 * q + 1 & 3) + 8 * (2 * q + 1 >> 2) + 4 * hi;
            ob[(size_t)c0 * CH_STRIDE] = fmaf(a3[2 * q],     s.x, a2[2 * q]);
            ob[(size_t)c1 * CH_STRIDE] = fmaf(a3[2 * q + 1], s.y, a2[2 * q + 1]);
        }
    };

    int d0  = rev ? (BD - 1) : 0;
    int sgn = rev ? -1 : 1;
    int oobq = rev ? -1 : BD;

    stage(d0 & 3, d0);
    stage((d0 + sgn) & 3, d0 + sgn);
    zero_slot((d0 - sgn) & 3);
    __syncthreads();

    f32x16 accP;
    {
        int q = d0 + 2 * sgn;
        if (q >= 0 && q < BD) stage(q & 3, q);
        accP = convd(d0);
        __syncthreads();
    }

    #pragma unroll 1
    for (int i = 1; i < BD; ++i) {
        int d = d0 + sgn * i;
        int q = d + 2 * sgn;
        if (q >= 0 && q < BD) stage(q & 3, q);
        else if (q == oobq)   zero_slot(q & 3);

        f32x16 acc = convd(d);      // 27 MFMAs — independent of tail below
        tail(accP, d - sgn);        // VALU/TRANS chain for previous d
        accP = acc;

        __syncthreads();
    }
    tail(accP, d0 + sgn * (BD - 1));
}

extern "C" void kernel_launch(void* const* d_in, const int* in_sizes, int n_in,
                              void* d_out, int out_size, void* d_ws, size_t ws_size,
                              hipStream_t stream)
{
    const float* inp = (const float*)d_in[0];
    const float* cw  = (const float*)d_in[1];
    const float* w1  = (const float*)d_in[2];
    const float* w2  = (const float*)d_in[3];
    const float* w3  = (const float*)d_in[4];
    const int*   rev = (const int*)d_in[5];

    ushort* wtab  = (ushort*)d_ws;                    // [0, 27648)
    ushort* wtab2 = (ushort*)((char*)d_ws + 27648);   // [27648, 31744)
    char*   xT    = (char*)d_ws + 32768;              // 65,011,712 B

    // 7936 xprep blocks + 62 weight-prep blocks, one launch
    xprep_kernel<<<dim3(7998), dim3(256), 0, stream>>>(
        inp, xT, cw, w1, w2, w3, wtab, wtab2);

    // 4b x 128ht = 512 blocks (2 per CU), persistent over all 31 d
    qrnn_fused<<<dim3(512), dim3(256), 0, stream>>>(
        xT, wtab, wtab2, (float*)d_out, rev);
}